// Round 19
// baseline (222.549 us; speedup 1.0000x reference)
//
#include <hip/hip_runtime.h>
#include <hip/hip_bf16.h>
#include <stdint.h>

typedef int i32x4 __attribute__((ext_vector_type(4)));
typedef int i32x8 __attribute__((ext_vector_type(8)));
typedef float f32x4 __attribute__((ext_vector_type(4)));

// ---------------------------------------------------------------------------
// Pass 1: binarize f32 -> fp4 e2m1 sign nibble (+1=0x2, -1=0xA, 0=0x0),
// packed 2 elems/byte, low nibble = lower k. VERBATIM round-14 v3 (~45 us).
// ---------------------------------------------------------------------------
__device__ __forceinline__ unsigned int sign_nib(float x) {
  return x > 0.0f ? 0x2u : (x < 0.0f ? 0xAu : 0x0u);
}

__device__ __forceinline__ unsigned short pack4(const float4& a) {
  return (unsigned short)(sign_nib(a.x)
                        | (sign_nib(a.y) << 4)
                        | (sign_nib(a.z) << 8)
                        | (sign_nib(a.w) << 12));
}

__global__ __launch_bounds__(256)
void binarize_fp4_v3(const float* __restrict__ x,
                     const float* __restrict__ w,
                     unsigned short* __restrict__ xb,
                     unsigned short* __restrict__ wb,
                     int bx) {
  const float4* src;
  unsigned short* dst;
  int b = blockIdx.x;
  if (b < bx) { src = (const float4*)x; dst = xb; }
  else        { src = (const float4*)w; dst = wb; b -= bx; }

  const size_t base = (size_t)b * 1024 + threadIdx.x;
  float4 v0 = src[base];
  float4 v1 = src[base + 256];
  float4 v2 = src[base + 512];
  float4 v3 = src[base + 768];

  dst[base]       = pack4(v0);
  dst[base + 256] = pack4(v1);
  dst[base + 512] = pack4(v2);
  dst[base + 768] = pack4(v3);
}

// ---------------------------------------------------------------------------
// Pass 2: C = A * B^T, fp4 +-1/0 inputs, MX-scaled 16x16x128 MFMA (scale=1),
// f32 out. EXACT (products +-1/0; |sum| <= 4096 exact in f32).
// Round 19: REVERT to the zero-conflict 16x16 geometry (R18's 32x32 had
// 6.29e6 bank conflicts = +5 us) and add a cross-tile A-fragment register
// pipeline with BUILTIN s_barrier:
//   per iter: waitvm(0); s_barrier; read bf(tt) [4 ds]; prefetch af(tt+1)
//   into the spare bank [8 ds, un-waited]; stage(tt+2); sched_barrier(0);
//   32 MFMAs on the CURRENT af bank (read last iter) + bf.
// The af-prefetch reads retire under the MFMA cluster (compiler's fine
// lgkm waits only block at the NEXT iter's first MFMA). The old asm
// "s_barrier"+"memory" clobber forced an lgkmcnt(0) drain at every barrier
// (R9's failure); builtin s_barrier does not.
// Banks statically named afA/afB, loop unrolled x2 (rule: runtime-indexed
// reg arrays go to scratch). Register budget: 92 VGPR + 32 (spare bank)
// + 128 acc ~= 252 <= 256 -> still 2 waves/SIMD; do NOT also pipeline B
// (+16 regs would exceed 256 and halve occupancy).
// Restage safety: stage(tt+2) rewrites buf (tt+2)&3, last read (af-prefetch)
// during iter tt-3 / (bf) iter tt-2 -- 2+ barriers separation.
// ---------------------------------------------------------------------------
__device__ __forceinline__ void load_lds16(const void* g, void* l) {
  __builtin_amdgcn_global_load_lds(
      (const __attribute__((address_space(1))) void*)g,
      (__attribute__((address_space(3))) void*)l,
      16, 0, 0);
}

template <int N>
__device__ __forceinline__ void waitvm() {
  asm volatile("s_waitcnt vmcnt(%0)" ::"i"(N) : "memory");
}

__device__ __forceinline__ i32x8 rd8(const char* p) {
  i32x4 q = *(const i32x4*)p;
  return __builtin_shufflevector(q, q, 0, 1, 2, 3, -1, -1, -1, -1);
}

__global__ __launch_bounds__(512, 2)
void gemm_bt_fp4(const unsigned char* __restrict__ A,
                 const unsigned char* __restrict__ B,
                 float* __restrict__ C,
                 int M, int N, int K, int nbn) {
  constexpr int BM = 256, BN = 256;
  __shared__ __attribute__((aligned(16))) char lds[4 * 32768];

  // XCD-aware bijective swizzle (grid = 32*16 = 512, multiple of 8)
  int nwg = gridDim.x;
  int bid = blockIdx.x;
  int cpx = nwg >> 3;
  int swz = (bid & 7) * cpx + (bid >> 3);
  int tm = swz / nbn;
  int tn = swz % nbn;

  const int t = threadIdx.x;
  const int lane = t & 63;
  const int wid = t >> 6;       // 0..7
  const int wm = wid >> 2;      // 0..1  (wave row: 128 rows)
  const int wn = wid & 3;       // 0..3  (wave col: 64 cols)
  const int lrow = lane & 15;
  const int kg = lane >> 4;     // 0..3 (32 contiguous fp4 k-elems = 16 B)

  const int Kb = K >> 1;        // row stride in bytes (fp4 packed)
  const size_t rowA0 = (size_t)tm * BM;
  const size_t rowB0 = (size_t)tn * BN;

  f32x4 acc[8][4] = {};

  const int nt = K / 128;  // 32

  // --- staging lane constants (inverse-swizzled global source) ---
  const int soff0 = wid * 1024 + lane * 16;
  const int srow0 = soff0 >> 6;
  const int scb0 = ((soff0 >> 4) & 3) ^ ((srow0 >> 1) & 3);
  const int soff1 = 8192 + wid * 1024 + lane * 16;
  const int srow1 = soff1 >> 6;
  const int scb1 = ((soff1 >> 4) & 3) ^ ((srow1 >> 1) & 3);

  auto stage = [&](int tt) {
    const int b = tt & 3;
    const int k0b = tt * 64;    // tile K-offset in BYTES (128 fp4 = 64 B)
    load_lds16(A + (rowA0 + srow0) * Kb + k0b + scb0 * 16,
               lds + b * 32768 + wid * 1024);
    load_lds16(A + (rowA0 + srow1) * Kb + k0b + scb1 * 16,
               lds + b * 32768 + 8192 + wid * 1024);
    load_lds16(B + (rowB0 + srow0) * Kb + k0b + scb0 * 16,
               lds + b * 32768 + 16384 + wid * 1024);
    load_lds16(B + (rowB0 + srow1) * Kb + k0b + scb1 * 16,
               lds + b * 32768 + 16384 + 8192 + wid * 1024);
  };

  // --- swizzled read column (byte) within a 64B LDS row (proven 0-conflict)
  const int rcol = ((kg ^ ((lrow >> 1) & 3)) << 4);
  const int aoff = (wm * 128 + lrow) * 64 + rcol;
  const int boff = 16384 + (wn * 64 + lrow) * 64 + rcol;

  const int SC = 0x7F7F7F7F;  // E8M0 scale bytes: 127 -> 2^0

  i32x8 afA[8], afB[8];

  // prologue: stage 0,1; sync stage(0); preload af(0) into bank A
  stage(0); stage(1);
  waitvm<4>();
  __builtin_amdgcn_s_barrier();
  {
    const char* Ab = lds + aoff;  // buffer 0
    #pragma unroll
    for (int m = 0; m < 8; ++m)
      afA[m] = rd8(Ab + m * 1024);
  }

  auto body = [&](i32x8 (&afC)[8], i32x8 (&afN)[8], int tt) {
    waitvm<0>();                       // my stage(tt+1) loads landed
    __builtin_amdgcn_s_barrier();      // everyone's stage(tt+1) landed
    const int b = tt & 3;
    const char* Bb = lds + b * 32768 + boff;
    i32x8 bf[4];
    #pragma unroll
    for (int n = 0; n < 4; ++n)
      bf[n] = rd8(Bb + n * 1024);
    if (tt + 1 < nt) {                 // prefetch next tile's A frags
      const char* Ab = lds + ((tt + 1) & 3) * 32768 + aoff;
      #pragma unroll
      for (int m = 0; m < 8; ++m)
        afN[m] = rd8(Ab + m * 1024);
    }
    if (tt + 2 < nt) stage(tt + 2);
    __builtin_amdgcn_sched_barrier(0); // keep reads/stage above the MFMAs
    #pragma unroll
    for (int m = 0; m < 8; ++m)
      #pragma unroll
      for (int n = 0; n < 4; ++n)
        acc[m][n] = __builtin_amdgcn_mfma_scale_f32_16x16x128_f8f6f4(
            afC[m], bf[n], acc[m][n], 4, 4, 0, SC, 0, SC);
  };

  for (int tt = 0; tt < nt; tt += 2) {
    body(afA, afB, tt);
    body(afB, afA, tt + 1);
  }

  // --- epilogue: 16x16 C/D layout col = lane&15, row = (lane>>4)*4 + r ---
  const size_t cRow0 = rowA0 + (size_t)wm * 128;
  const size_t cCol0 = rowB0 + (size_t)wn * 64;
  const int orow = kg * 4;
  #pragma unroll
  for (int m = 0; m < 8; ++m)
    #pragma unroll
    for (int n = 0; n < 4; ++n)
      #pragma unroll
      for (int r = 0; r < 4; ++r)
        C[(cRow0 + m * 16 + orow + r) * N + cCol0 + n * 16 + lrow] =
            acc[m][n][r];
}

// ---------------------------------------------------------------------------
extern "C" void kernel_launch(void* const* d_in, const int* in_sizes, int n_in,
                              void* d_out, int out_size, void* d_ws, size_t ws_size,
                              hipStream_t stream) {
  const float* x = (const float*)d_in[0];
  const float* w = (const float*)d_in[1];
  float* out = (float*)d_out;

  const int K = 4096;
  const int M = in_sizes[0] / K;   // 8192
  const int N = in_sizes[1] / K;   // 4096

  unsigned char* xb = (unsigned char*)d_ws;
  unsigned char* wb = xb + (size_t)M * (K / 2);

  int bxx = (M * K) / 4096;        // 8192
  int bxw = (N * K) / 4096;        // 4096
  binarize_fp4_v3<<<dim3(bxx + bxw), dim3(256), 0, stream>>>(
      x, w, (unsigned short*)xb, (unsigned short*)wb, bxx);

  int nbm = M / 256;  // 32
  int nbn = N / 256;  // 16
  gemm_bt_fp4<<<dim3(nbm * nbn), dim3(512), 0, stream>>>(
      xb, wb, out, M, N, K, nbn);
}

// Round 20
// 119.966 us; speedup vs baseline: 1.8551x; 1.8551x over previous
//
#include <hip/hip_runtime.h>
#include <hip/hip_bf16.h>
#include <stdint.h>

typedef int i32x4 __attribute__((ext_vector_type(4)));
typedef int i32x8 __attribute__((ext_vector_type(8)));
typedef float f32x4 __attribute__((ext_vector_type(4)));

// ---------------------------------------------------------------------------
// Pass 1: binarize f32 -> fp4 e2m1 sign nibble (+1=0x2, -1=0xA, 0=0x0),
// packed 2 elems/byte, low nibble = lower k. VERBATIM round-14 v3
// (best-measured binarize: ~45 us; 6 structural variants all 45-55 us).
// ---------------------------------------------------------------------------
__device__ __forceinline__ unsigned int sign_nib(float x) {
  return x > 0.0f ? 0x2u : (x < 0.0f ? 0xAu : 0x0u);
}

__device__ __forceinline__ unsigned short pack4(const float4& a) {
  return (unsigned short)(sign_nib(a.x)
                        | (sign_nib(a.y) << 4)
                        | (sign_nib(a.z) << 8)
                        | (sign_nib(a.w) << 12));
}

__global__ __launch_bounds__(256)
void binarize_fp4_v3(const float* __restrict__ x,
                     const float* __restrict__ w,
                     unsigned short* __restrict__ xb,
                     unsigned short* __restrict__ wb,
                     int bx) {   // bx = number of blocks covering x
  const float4* src;
  unsigned short* dst;
  int b = blockIdx.x;
  if (b < bx) { src = (const float4*)x; dst = xb; }
  else        { src = (const float4*)w; dst = wb; b -= bx; }

  const size_t base = (size_t)b * 1024 + threadIdx.x;
  float4 v0 = src[base];
  float4 v1 = src[base + 256];
  float4 v2 = src[base + 512];
  float4 v3 = src[base + 768];

  dst[base]       = pack4(v0);
  dst[base + 256] = pack4(v1);
  dst[base + 512] = pack4(v2);
  dst[base + 768] = pack4(v3);
}

// ---------------------------------------------------------------------------
// Pass 2: C = A * B^T, fp4 +-1/0 inputs, MX-scaled 16x16x128 MFMA (scale=1),
// f32 out. EXACT: products +-1/0; f32 accumulation of <=4096 integers exact.
// VERBATIM round-14 GEMM -- the best-measured configuration (75 us, 51% of
// the 7228 TF fp4 ceiling, 0 bank conflicts, within ~10% of this
// structure's serial-pipe floor of 2555 cyc/tile).
//
// SCHEDULE-GRAFT LEDGER (do not retry; all falsified by A/B this session):
//  - asm-barrier fragment pipeline: lgkm drain at barrier        (R9,  -7%)
//  - 32x32 MFMA geometry: bank conflicts under any XOR variant   (R10/R18)
//  - small tiles for occupancy: L2 locality lost, FETCH 3.5x     (R11, -50%)
//  - register af-pipeline: acc spill, WRITE_SIZE 131->372 MB     (R19, -150%)
// Constraint: acc=128 unified regs/wave -> 1 block/CU, 2 waves/SIMD,
// ~252-reg ceiling -> no register headroom for intra-wave pipelining and
// no occupancy headroom for cross-block overlap. Matches guide m131-m141.
// ---------------------------------------------------------------------------
__device__ __forceinline__ void load_lds16(const void* g, void* l) {
  __builtin_amdgcn_global_load_lds(
      (const __attribute__((address_space(1))) void*)g,
      (__attribute__((address_space(3))) void*)l,
      16, 0, 0);
}

__device__ __forceinline__ void bar() {
  asm volatile("s_barrier" ::: "memory");
}
template <int N>
__device__ __forceinline__ void waitvm() {
  asm volatile("s_waitcnt vmcnt(%0)" ::"i"(N) : "memory");
}

__device__ __forceinline__ i32x8 rd8(const char* p) {
  i32x4 q = *(const i32x4*)p;
  return __builtin_shufflevector(q, q, 0, 1, 2, 3, -1, -1, -1, -1);
}

__global__ __launch_bounds__(512, 2)
void gemm_bt_fp4(const unsigned char* __restrict__ A,
                 const unsigned char* __restrict__ B,
                 float* __restrict__ C,
                 int M, int N, int K, int nbn) {
  constexpr int BM = 256, BN = 256;
  __shared__ __attribute__((aligned(16))) char lds[4 * 32768];

  // XCD-aware bijective swizzle (grid = 32*16 = 512, multiple of 8)
  int nwg = gridDim.x;
  int bid = blockIdx.x;
  int cpx = nwg >> 3;
  int swz = (bid & 7) * cpx + (bid >> 3);
  int tm = swz / nbn;
  int tn = swz % nbn;

  const int t = threadIdx.x;
  const int lane = t & 63;
  const int wid = t >> 6;       // 0..7
  const int wm = wid >> 2;      // 0..1  (wave row: 128 rows)
  const int wn = wid & 3;       // 0..3  (wave col: 64 cols)
  const int lrow = lane & 15;
  const int kg = lane >> 4;     // 0..3 (32 contiguous fp4 k-elems = 16 B)

  const int Kb = K >> 1;        // row stride in bytes (fp4 packed)
  const size_t rowA0 = (size_t)tm * BM;
  const size_t rowB0 = (size_t)tn * BN;

  f32x4 acc[8][4] = {};

  const int nt = K / 128;  // 32

  // --- staging lane constants (inverse-swizzled global source) ---
  const int soff0 = wid * 1024 + lane * 16;
  const int srow0 = soff0 >> 6;
  const int scb0 = ((soff0 >> 4) & 3) ^ ((srow0 >> 1) & 3);
  const int soff1 = 8192 + wid * 1024 + lane * 16;
  const int srow1 = soff1 >> 6;
  const int scb1 = ((soff1 >> 4) & 3) ^ ((srow1 >> 1) & 3);

  auto stage = [&](int tt) {
    const int b = tt & 3;
    const int k0b = tt * 64;    // tile K-offset in BYTES (128 fp4 = 64 B)
    load_lds16(A + (rowA0 + srow0) * Kb + k0b + scb0 * 16,
               lds + b * 32768 + wid * 1024);
    load_lds16(A + (rowA0 + srow1) * Kb + k0b + scb1 * 16,
               lds + b * 32768 + 8192 + wid * 1024);
    load_lds16(B + (rowB0 + srow0) * Kb + k0b + scb0 * 16,
               lds + b * 32768 + 16384 + wid * 1024);
    load_lds16(B + (rowB0 + srow1) * Kb + k0b + scb1 * 16,
               lds + b * 32768 + 16384 + 8192 + wid * 1024);
  };

  // --- swizzled read column (byte) within a 64B LDS row (proven 0-conflict)
  const int rcol = ((kg ^ ((lrow >> 1) & 3)) << 4);
  const int aoff = (wm * 128 + lrow) * 64 + rcol;
  const int boff = 16384 + (wn * 64 + lrow) * 64 + rcol;

  const int SC = 0x7F7F7F7F;  // E8M0 scale bytes: 127 -> 2^0

  // prologue: stage tiles 0 and 1 (8 loads outstanding per thread)
  stage(0); stage(1);

  for (int tt = 0; tt < nt; ++tt) {
    const int b = tt & 3;
    if (tt + 1 < nt) waitvm<4>(); else waitvm<0>();
    bar();  // the only barrier per tile

    const char* Ab = lds + b * 32768 + aoff;
    const char* Bb = lds + b * 32768 + boff;

    // half-phase 1: B frags + A frags 0..3, restage, 16 MFMAs
    i32x8 bf[4], af[4];
    #pragma unroll
    for (int n = 0; n < 4; ++n)
      bf[n] = rd8(Bb + n * 1024);
    #pragma unroll
    for (int m = 0; m < 4; ++m)
      af[m] = rd8(Ab + m * 1024);

    if (tt + 2 < nt) stage(tt + 2);

    #pragma unroll
    for (int m = 0; m < 4; ++m)
      #pragma unroll
      for (int n = 0; n < 4; ++n)
        acc[m][n] = __builtin_amdgcn_mfma_scale_f32_16x16x128_f8f6f4(
            af[m], bf[n], acc[m][n], 4, 4, 0, SC, 0, SC);

    // half-phase 2: A frags 4..7, 16 MFMAs
    i32x8 ag[4];
    #pragma unroll
    for (int m = 0; m < 4; ++m)
      ag[m] = rd8(Ab + (m + 4) * 1024);

    #pragma unroll
    for (int m = 0; m < 4; ++m)
      #pragma unroll
      for (int n = 0; n < 4; ++n)
        acc[m + 4][n] = __builtin_amdgcn_mfma_scale_f32_16x16x128_f8f6f4(
            ag[m], bf[n], acc[m + 4][n], 4, 4, 0, SC, 0, SC);
  }

  // --- epilogue: 16x16 C/D layout col = lane&15, row = (lane>>4)*4 + r ---
  const size_t cRow0 = rowA0 + (size_t)wm * 128;
  const size_t cCol0 = rowB0 + (size_t)wn * 64;
  const int orow = kg * 4;
  #pragma unroll
  for (int m = 0; m < 8; ++m)
    #pragma unroll
    for (int n = 0; n < 4; ++n)
      #pragma unroll
      for (int r = 0; r < 4; ++r)
        C[(cRow0 + m * 16 + orow + r) * N + cCol0 + n * 16 + lrow] =
            acc[m][n][r];
}

// ---------------------------------------------------------------------------
extern "C" void kernel_launch(void* const* d_in, const int* in_sizes, int n_in,
                              void* d_out, int out_size, void* d_ws, size_t ws_size,
                              hipStream_t stream) {
  const float* x = (const float*)d_in[0];
  const float* w = (const float*)d_in[1];
  float* out = (float*)d_out;

  const int K = 4096;
  const int M = in_sizes[0] / K;   // 8192
  const int N = in_sizes[1] / K;   // 4096

  unsigned char* xb = (unsigned char*)d_ws;
  unsigned char* wb = xb + (size_t)M * (K / 2);

  // round-14 binarize: each block = 4096 floats, lane-contiguous
  int bxx = (M * K) / 4096;        // 8192
  int bxw = (N * K) / 4096;        // 4096
  binarize_fp4_v3<<<dim3(bxx + bxw), dim3(256), 0, stream>>>(
      x, w, (unsigned short*)xb, (unsigned short*)wb, bxx);

  int nbm = M / 256;  // 32
  int nbn = N / 256;  // 16
  gemm_bt_fp4<<<dim3(nbm * nbn), dim3(512), 0, stream>>>(
      xb, wb, out, M, N, K, nbn);
}